// Round 5
// baseline (1591.027 us; speedup 1.0000x reference)
//
#include <hip/hip_runtime.h>

// StreamingPCEN: x [B=16, MICS=4, T=2048, F=257] fp32  (539 MB in, 539 MB out).
// M_t = (1-s) M_{t-1} + s x_t, M_0 = x_0; out = (x/(M+eps)^alpha + delta)^r - delta^r.
//
// Round-5 theory: all prior kernels sit at a ~14 TB/s L2<->L3/HBM fabric
// ceiling (r0: 2.05 GB L2-level traffic / 137 us = 15 TB/s; two-phase r2-r4:
// 1.62 GB / ~120 us = 13.5 TB/s). The only lever left is TRAFFIC: read x
// ONCE. Single-pass decoupled-lookback scan:
//   * ticket-ordered virtual blocks (atomic counter) -> claimed tickets are
//     always a prefix of the order; every spin target has a smaller ticket
//     -> rigorously deadlock-free without co-residency assumptions.
//   * block (bm, c) stages its 32-frame chunk (32x1028 B = 32.9 KB) into LDS
//     with float4 loads (8+1 per thread, all independent -> deep MLP),
//   * computes the zero-init local EMA end-state E_loc (c==0: fixed-point
//     init m=x_0), publishes it with device-scope atomics + release flag
//     (cross-XCD safe; __syncthreads drains vmcnt before the flag store),
//   * folds predecessors' E_loc into the exact carry (<=63 fmas, 4-wide
//     batched loads), depth-1 dependency -- fully parallel across blocks,
//   * emits the 128 output frames from the LDS-resident chunk (NT stores).
// L2-level traffic: 539 r + 539 w + ~8 MB states = 1.08 GB (was 1.62).
// Exact algorithm (same math as the verified two-phase r2-r4).

#define EPS 1e-6f

constexpr int BM = 64;         // B*MICS
constexpr int T  = 2048;
constexpr int F  = 257;
constexpr int LR = 32;         // frames per chunk
constexpr int CC = T / LR;     // 64 chunks per bm row
constexpr int NV = BM * CC;    // 4096 virtual blocks
// ws layout (ints): [0] ticket ctr, [16..16+NV) flags, then mval floats
constexpr int    WS_FLG    = 16;
constexpr int    WS_VAL    = WS_FLG + NV;                   // 4112 (16B-aligned)
constexpr size_t WS_BYTES  = ((size_t)WS_VAL + (size_t)NV * F) * 4;

__device__ __forceinline__ float fast_exp2(float x) { return __builtin_amdgcn_exp2f(x); }
__device__ __forceinline__ float fast_log2(float x) { return __builtin_amdgcn_logf(x); }

__device__ __forceinline__ float pcen_nl(float xv, float m, float alpha,
                                         float delta, float r, float dr) {
  float inner = fmaf(xv, fast_exp2(-alpha * fast_log2(m + EPS)), delta);
  return fast_exp2(r * fast_log2(inner)) - dr;
}

// ---- init: zero ticket counter + flags (runs every graph replay) ----
__global__ __launch_bounds__(256) void pcen_init(int* __restrict__ wsi) {
  for (int k = threadIdx.x; k < WS_VAL; k += 256) wsi[k] = 0;
}

// ---- single-pass decoupled-lookback PCEN ----
__global__ __launch_bounds__(256, 4) void pcen_lookback(
    const float* __restrict__ x, const float* __restrict__ s_p,
    const float* __restrict__ alpha_p, const float* __restrict__ delta_p,
    const float* __restrict__ r_p, float* __restrict__ ws,
    float* __restrict__ out) {
  __shared__ float sb[LR * F];           // 32896 B -> 4 blocks/CU, 16 waves/CU
  __shared__ int vshare;
  const int tid = threadIdx.x;

  int* wsi   = (int*)ws;
  int* flags = wsi + WS_FLG;
  float* mval = ws + WS_VAL;

  if (tid == 0)
    vshare = __hip_atomic_fetch_add(wsi, 1, __ATOMIC_RELAXED,
                                    __HIP_MEMORY_SCOPE_AGENT);
  __syncthreads();
  const int v  = vshare;
  const int bm = v >> 6;                 // v / CC
  const int c  = v & (CC - 1);           // v % CC

  const float s     = s_p[0];
  const float a     = 1.0f - s;
  const float alpha = alpha_p[0];
  const float delta = delta_p[0];
  const float r     = r_p[0];
  const float dr    = fast_exp2(r * fast_log2(delta));

  float aL = a;                          // a^32 via 5 squarings
  #pragma unroll
  for (int i = 0; i < 5; ++i) aL *= aL;

  // ---- stage chunk into LDS: 2056 float4 = 256x8 + 8, all independent ----
  const size_t base = ((size_t)bm * T + (size_t)c * LR) * F;
  const float4* src = reinterpret_cast<const float4*>(x + base);
  float4* sb4 = reinterpret_cast<float4*>(sb);
  {
    float4 vv[8]; float4 vt;
    #pragma unroll
    for (int q = 0; q < 8; ++q) vv[q] = src[q * 256 + tid];
    if (tid < 8) vt = src[2048 + tid];
    #pragma unroll
    for (int q = 0; q < 8; ++q) sb4[q * 256 + tid] = vv[q];
    if (tid < 8) sb4[2048 + tid] = vt;
  }
  __syncthreads();

  // ---- local zero-init EMA end-state (c==0: fixed-point init m=x_0) ----
  // LDS bank: (t*257 + tid) % 32 = (t + tid) % 32 -> 2 lanes/bank = free.
  float m = (c == 0) ? sb[tid] : 0.0f;
  #pragma unroll 8
  for (int t = 0; t < LR; ++t) m = fmaf(a, m, s * sb[t * F + tid]);
  float mt = 0.0f;                       // tail column f=256, owned by tid 0
  if (tid == 0) {
    mt = (c == 0) ? sb[256] : 0.0f;
    for (int t = 0; t < LR; ++t) mt = fmaf(a, mt, s * sb[t * F + 256]);
  }

  // ---- publish E_loc (device-scope; flag after vmcnt-drain barrier) ----
  if (c < CC - 1) {
    __hip_atomic_store(&mval[(size_t)v * F + tid], m, __ATOMIC_RELAXED,
                       __HIP_MEMORY_SCOPE_AGENT);
    if (tid == 0)
      __hip_atomic_store(&mval[(size_t)v * F + 256], mt, __ATOMIC_RELAXED,
                         __HIP_MEMORY_SCOPE_AGENT);
    __syncthreads();                     // emits s_waitcnt vmcnt(0) + barrier
    if (tid == 0) {
      __threadfence();
      __hip_atomic_store(&flags[v], 1, __ATOMIC_RELEASE,
                         __HIP_MEMORY_SCOPE_AGENT);
    }
  }

  // ---- lookback: exact carry = sum_j aL^(c-1-j) E_loc(j), depth-1 dep ----
  float carry = 0.0f, carryt = 0.0f;
  if (c > 0) {
    if (tid == 0) {
      const int jbase = bm * CC;
      for (int j = jbase; j < v; ++j)
        while (__hip_atomic_load(&flags[j], __ATOMIC_ACQUIRE,
                                 __HIP_MEMORY_SCOPE_AGENT) == 0)
          __builtin_amdgcn_s_sleep(2);
    }
    __syncthreads();
    const float* mv = mval + (size_t)(bm * CC) * F;
    const float aL2 = aL * aL, aL3 = aL2 * aL, aL4 = aL2 * aL2;
    int j = 0;
    for (; j + 4 <= c; j += 4) {         // 4 independent loads per iter
      float e0 = __hip_atomic_load(&mv[(size_t)(j + 0) * F + tid],
                                   __ATOMIC_RELAXED, __HIP_MEMORY_SCOPE_AGENT);
      float e1 = __hip_atomic_load(&mv[(size_t)(j + 1) * F + tid],
                                   __ATOMIC_RELAXED, __HIP_MEMORY_SCOPE_AGENT);
      float e2 = __hip_atomic_load(&mv[(size_t)(j + 2) * F + tid],
                                   __ATOMIC_RELAXED, __HIP_MEMORY_SCOPE_AGENT);
      float e3 = __hip_atomic_load(&mv[(size_t)(j + 3) * F + tid],
                                   __ATOMIC_RELAXED, __HIP_MEMORY_SCOPE_AGENT);
      carry = fmaf(aL4, carry, fmaf(aL3, e0, fmaf(aL2, e1, fmaf(aL, e2, e3))));
    }
    for (; j < c; ++j) {
      float e = __hip_atomic_load(&mv[(size_t)j * F + tid],
                                  __ATOMIC_RELAXED, __HIP_MEMORY_SCOPE_AGENT);
      carry = fmaf(aL, carry, e);
    }
    if (tid == 0) {
      for (int jj = 0; jj < c; ++jj) {
        float e = __hip_atomic_load(&mv[(size_t)jj * F + 256],
                                    __ATOMIC_RELAXED, __HIP_MEMORY_SCOPE_AGENT);
        carryt = fmaf(aL, carryt, e);
      }
    }
  }

  // ---- outputs from the LDS-resident chunk (x read from HBM exactly once) --
  float mr = (c == 0) ? sb[tid] : carry;
  float* op = out + base;
  #pragma unroll 4
  for (int t = 0; t < LR; ++t) {
    float xv = sb[t * F + tid];
    mr = fmaf(a, mr, s * xv);
    __builtin_nontemporal_store(pcen_nl(xv, mr, alpha, delta, r, dr),
                                &op[t * F + tid]);
  }
  if (tid == 0) {
    float mrt = (c == 0) ? sb[256] : carryt;
    for (int t = 0; t < LR; ++t) {
      float xv = sb[t * F + 256];
      mrt = fmaf(a, mrt, s * xv);
      __builtin_nontemporal_store(pcen_nl(xv, mrt, alpha, delta, r, dr),
                                  &op[t * F + 256]);
    }
  }
}

// ---- fallback (no/small ws): truncated-history single pass (r3-style) ----
constexpr int FB_L = 128;
constexpr int FB_C = T / FB_L;
constexpr int FB_H = 256;
__global__ __launch_bounds__(64, 4) void pcen_fb_nows(
    const float* __restrict__ x, const float* __restrict__ s_p,
    const float* __restrict__ alpha_p, const float* __restrict__ delta_p,
    const float* __restrict__ r_p, float* __restrict__ out) {
  const int b  = blockIdx.x;
  const int l  = threadIdx.x;
  const int bm = b / FB_C;
  const int c  = b % FB_C;

  const float s     = s_p[0];
  const float a     = 1.0f - s;
  const float alpha = alpha_p[0];
  const float delta = delta_p[0];
  const float r     = r_p[0];
  const float dr    = fast_exp2(r * fast_log2(delta));

  const size_t colbase = (size_t)bm * T * F;
  const int tstart = c * FB_L;
  int t0 = tstart - FB_H; if (t0 < 0) t0 = 0;

  float m0, m1, m2, m3, m4;
  const float* row0 = x + colbase + (size_t)t0 * F;
  if (t0 == 0) {
    m0 = row0[l]; m1 = row0[l + 64]; m2 = row0[l + 128]; m3 = row0[l + 192];
    m4 = row0[256];
  } else {
    m0 = m1 = m2 = m3 = m4 = 0.0f;
  }

  const float* p = row0;
  for (int t = t0; t < tstart; ++t) {
    float x0 = p[l], x1 = p[l + 64], x2 = p[l + 128], x3 = p[l + 192], x4 = p[256];
    m0 = fmaf(a, m0, s * x0); m1 = fmaf(a, m1, s * x1);
    m2 = fmaf(a, m2, s * x2); m3 = fmaf(a, m3, s * x3);
    m4 = fmaf(a, m4, s * x4);
    p += F;
  }
  p = x + colbase + (size_t)tstart * F;
  float* op = out + colbase + (size_t)tstart * F;
  for (int t = 0; t < FB_L; ++t) {
    float x0 = p[l], x1 = p[l + 64], x2 = p[l + 128], x3 = p[l + 192], x4 = p[256];
    m0 = fmaf(a, m0, s * x0); m1 = fmaf(a, m1, s * x1);
    m2 = fmaf(a, m2, s * x2); m3 = fmaf(a, m3, s * x3);
    m4 = fmaf(a, m4, s * x4);
    __builtin_nontemporal_store(pcen_nl(x0, m0, alpha, delta, r, dr), &op[l]);
    __builtin_nontemporal_store(pcen_nl(x1, m1, alpha, delta, r, dr), &op[l + 64]);
    __builtin_nontemporal_store(pcen_nl(x2, m2, alpha, delta, r, dr), &op[l + 128]);
    __builtin_nontemporal_store(pcen_nl(x3, m3, alpha, delta, r, dr), &op[l + 192]);
    if (l == 0)
      __builtin_nontemporal_store(pcen_nl(x4, m4, alpha, delta, r, dr), &op[256]);
    p  += F;
    op += F;
  }
}

extern "C" void kernel_launch(void* const* d_in, const int* in_sizes, int n_in,
                              void* d_out, int out_size, void* d_ws, size_t ws_size,
                              hipStream_t stream) {
  const float* x     = (const float*)d_in[0];
  const float* s     = (const float*)d_in[1];
  const float* alpha = (const float*)d_in[2];
  const float* delta = (const float*)d_in[3];
  const float* r     = (const float*)d_in[4];
  float* out = (float*)d_out;

  if (d_ws != nullptr && ws_size >= WS_BYTES) {
    pcen_init<<<1, 256, 0, stream>>>((int*)d_ws);
    pcen_lookback<<<NV, 256, 0, stream>>>(x, s, alpha, delta, r,
                                          (float*)d_ws, out);
  } else {
    pcen_fb_nows<<<BM * FB_C, 64, 0, stream>>>(x, s, alpha, delta, r, out);
  }
}

// Round 7
// 286.527 us; speedup vs baseline: 5.5528x; 5.5528x over previous
//
#include <hip/hip_runtime.h>

// StreamingPCEN: x [B=16, MICS=4, T=2048, F=257] fp32 (134.7 MB in, 134.7 MB out).
// M_t = (1-s) M_{t-1} + s x_t, M_0 = x_0; out = (x/(M+eps)^alpha + delta)^r - delta^r.
//
// Round-7 = round-6 with the compile fix (__builtin_nontemporal_store needs a
// clang ext_vector type, not HIP's float4 class). Theory unchanged:
// single-dispatch truncated-warmup scan (H=256, c<=1 exact; r0-proven absmax
// 0.0039) with STRUCTURAL load concurrency via global_load_lds DMA:
//  * block = 1 wave owns (bm, chunk of L=128 frames); grid 64x16=1024 = 4/CU.
//  * tiles of 16 frames = 16448 B are 16B-aligned flat ranges -> staged with
//    17 global_load_lds dwordx4 issues into a double-buffered LDS slot pair
//    (2 x 16448 B = 32.9 KB).
//  * counted waits (T4): s_waitcnt vmcnt(34/17) keeps the next tile's DMA and
//    the previous out-tile's stores in flight; never drains to 0 mid-loop.
//    The DMA queue cannot be re-serialized by regalloc (rounds 1-4 failure:
//    VGPR-staged batches collapsed to MLP~1.5 -> 2.9-3.7 TB/s).
//  * per frame, lane owns cols {lane,+64,+128,+192}, col 256 broadcast; LDS
//    bank = (f + lane) % 32 -> 2 lanes/bank = free.
//  * outputs overwrite the consumed LDS slot in place, then one flat flush of
//    17 f32x4 NT stores per tile -> outstanding vmem <= 51 < 63.

#define EPS 1e-6f

constexpr int T   = 2048;
constexpr int F   = 257;
constexpr int L   = 128;               // output frames per block
constexpr int NCH = T / L;             // 16 chunks per bm row
constexpr int TFR = 16;                // frames per tile
constexpr int TILE_BYTES = TFR * F * 4;  // 16448, 16B-aligned
constexpr int OUT_TILES  = L / TFR;      // 8

typedef float f32x4 __attribute__((ext_vector_type(4)));

__device__ __forceinline__ float fast_exp2(float x) { return __builtin_amdgcn_exp2f(x); }
__device__ __forceinline__ float fast_log2(float x) { return __builtin_amdgcn_logf(x); }

__device__ __forceinline__ float pcen_nl(float xv, float m, float alpha,
                                         float delta, float r, float dr) {
  float inner = fmaf(xv, fast_exp2(-alpha * fast_log2(m + EPS)), delta);
  return fast_exp2(r * fast_log2(inner)) - dr;
}

typedef const __attribute__((address_space(1))) unsigned int* gas1;
typedef __attribute__((address_space(3))) unsigned int* las3;

// 16 B per lane direct global->LDS DMA (dest = uniform base + lane*16).
__device__ __forceinline__ void dma16(const void* g, void* l) {
  __builtin_amdgcn_global_load_lds((gas1)g, (las3)l, 16, 0, 0);
}

// s_waitcnt imm: vmcnt bits [3:0]+[15:14], expcnt [6:4]=7, lgkmcnt [11:8]=15.
constexpr int wenc(int vm) {
  return (vm & 15) | (7 << 4) | (15 << 8) | ((vm >> 4) << 14);
}

__global__ __launch_bounds__(64, 1) void pcen_dma(
    const float* __restrict__ x, const float* __restrict__ s_p,
    const float* __restrict__ alpha_p, const float* __restrict__ delta_p,
    const float* __restrict__ r_p, float* __restrict__ out) {
  __shared__ f32x4 slots[2][TFR * F / 4];   // 2 x 16448 B
  const int lane = threadIdx.x;
  const int bm   = blockIdx.x >> 4;
  const int c    = blockIdx.x & (NCH - 1);

  const float s     = s_p[0];
  const float a     = 1.0f - s;
  const float alpha = alpha_p[0];
  const float delta = delta_p[0];
  const float r     = r_p[0];
  const float dr    = fast_exp2(r * fast_log2(delta));

  // warmup: c==0 none (exact, fixed-point init m=x_0); c==1 exact 128 frames
  // from stream start; c>=2 truncated 256 frames (a^256 ~ 1.5e-3).
  const int  warmT  = (c == 0) ? 0 : (c == 1 ? 8 : 16);
  const int  NT     = warmT + OUT_TILES;
  const bool exact0 = (c <= 1);
  const int  startFrame = (c <= 1) ? 0 : (c * L - 256);

  const char* gx   = (const char*)x  + ((size_t)bm * T + (size_t)startFrame) * (F * 4);
  char*       gout = (char*)out      + ((size_t)bm * T + (size_t)c * L) * (F * 4);

  auto issue = [&](int ti) {
    const char* g = gx + (size_t)ti * TILE_BYTES;
    char* lb = (char*)&slots[ti & 1][0];
    #pragma unroll
    for (int k = 0; k < 16; ++k)
      dma16(g + k * 1024 + lane * 16, lb + k * 1024);
    if (lane < 4)                       // tail: float4s 1024..1027
      dma16(g + 16384 + lane * 16, lb + 16384);
  };

  issue(0);
  float m0 = 0.f, m1 = 0.f, m2 = 0.f, m3 = 0.f, m4 = 0.f;

  for (int ti = 0; ti < NT; ++ti) {
    if (ti + 1 < NT) issue(ti + 1);
    __builtin_amdgcn_sched_barrier(0);
    // wait for tile ti's 17 DMAs; keep newer ops in flight:
    //   next tile's 17 DMAs (+17) and previous out-tile's 17 stores (+17).
    const bool nxt = (ti + 1 < NT);
    const bool pst = (ti >= 1) && (ti - 1 >= warmT);
    if (nxt && pst)      __builtin_amdgcn_s_waitcnt(wenc(34));
    else if (nxt || pst) __builtin_amdgcn_s_waitcnt(wenc(17));
    else                 __builtin_amdgcn_s_waitcnt(wenc(0));
    __builtin_amdgcn_sched_barrier(0);

    float* sp = (float*)&slots[ti & 1][0];

    if (ti < warmT) {                   // ---- warmup tile: EMA only ----
      #pragma unroll
      for (int f = 0; f < TFR; ++f) {
        float x0 = sp[f * F + lane];
        float x1 = sp[f * F + 64 + lane];
        float x2 = sp[f * F + 128 + lane];
        float x3 = sp[f * F + 192 + lane];
        float x4 = sp[f * F + 256];
        if (exact0 && ti == 0 && f == 0) {  // fixed-point init at stream start
          m0 = x0; m1 = x1; m2 = x2; m3 = x3; m4 = x4;
        }
        m0 = fmaf(a, m0, s * x0); m1 = fmaf(a, m1, s * x1);
        m2 = fmaf(a, m2, s * x2); m3 = fmaf(a, m3, s * x3);
        m4 = fmaf(a, m4, s * x4);
      }
    } else {                            // ---- output tile ----
      #pragma unroll
      for (int f = 0; f < TFR; ++f) {
        float x0 = sp[f * F + lane];
        float x1 = sp[f * F + 64 + lane];
        float x2 = sp[f * F + 128 + lane];
        float x3 = sp[f * F + 192 + lane];
        float x4 = sp[f * F + 256];
        if (exact0 && ti == 0 && f == 0) {  // c==0 only (warmT==0)
          m0 = x0; m1 = x1; m2 = x2; m3 = x3; m4 = x4;
        }
        m0 = fmaf(a, m0, s * x0); m1 = fmaf(a, m1, s * x1);
        m2 = fmaf(a, m2, s * x2); m3 = fmaf(a, m3, s * x3);
        m4 = fmaf(a, m4, s * x4);
        // overwrite consumed x bytes in place with outputs
        sp[f * F + lane]       = pcen_nl(x0, m0, alpha, delta, r, dr);
        sp[f * F + 64 + lane]  = pcen_nl(x1, m1, alpha, delta, r, dr);
        sp[f * F + 128 + lane] = pcen_nl(x2, m2, alpha, delta, r, dr);
        sp[f * F + 192 + lane] = pcen_nl(x3, m3, alpha, delta, r, dr);
        if (lane == 0)
          sp[f * F + 256] = pcen_nl(x4, m4, alpha, delta, r, dr);
      }
      // flat flush: 17 f32x4 NT stores (coalesced 1 KB/instr)
      char* go = gout + (size_t)(ti - warmT) * TILE_BYTES;
      char* lb = (char*)sp;
      #pragma unroll
      for (int k = 0; k < 16; ++k) {
        f32x4 v = *(const f32x4*)(lb + k * 1024 + lane * 16);
        __builtin_nontemporal_store(v, (f32x4*)(go + k * 1024 + lane * 16));
      }
      if (lane < 4) {
        f32x4 v = *(const f32x4*)(lb + 16384 + lane * 16);
        __builtin_nontemporal_store(v, (f32x4*)(go + 16384 + lane * 16));
      }
    }
  }
}

extern "C" void kernel_launch(void* const* d_in, const int* in_sizes, int n_in,
                              void* d_out, int out_size, void* d_ws, size_t ws_size,
                              hipStream_t stream) {
  const float* x     = (const float*)d_in[0];
  const float* s     = (const float*)d_in[1];
  const float* alpha = (const float*)d_in[2];
  const float* delta = (const float*)d_in[3];
  const float* r     = (const float*)d_in[4];
  float* out = (float*)d_out;

  pcen_dma<<<64 * NCH, 64, 0, stream>>>(x, s, alpha, delta, r, out);
}